// Round 9
// baseline (215.514 us; speedup 1.0000x reference)
//
#include <hip/hip_runtime.h>
#include <hip/hip_fp16.h>
#include <stdint.h>

// ---------------------------------------------------------------------------
// ThreeBodyLayer fused kernel v15 (MI355X / gfx950)
//
// All-f16 MFMA pipeline, log2-domain softplus. Scale algebra: W1/b1 carry
// log2(e); W2 carries ln2*log2(e)=1; b2*L2E; W3*LN2.
//
// v15 vs v14 (43us plateau; ~53% issue-busy, rest = per-wave dependency
// stalls on the serial trans chains; register pipelining compiler-blocked):
//  - PHASE-MERGED TILES: block owns 4 batch tiles of 16. Each barrier
//    region runs phase-2(tile k) AND phase-1(tile k+1) in the same wave's
//    instruction stream -> two independent dep-chains per wave; scheduler
//    fills trans-latency gaps with P1's MFMA/cvt/LDS-writes. No cross-
//    region unions (v8/v13 lesson): all state loop-local, fA as plain
//    float4, Xf consumed adjacently.
//  - T double-buffered 2x26KB + 2x1KB partials = 55.3KB LDS -> 2 blocks/CU
//    = 32 waves/CU; grid 512 -> every block resident, zero dispatch rounds.
//  - W1 frags straight from ws L2 image (v11 path; latency now overlapped).
//  - x HBM loads issue at region top (~1-2K cyc cover before P1 uses them).
//  - Deferred output: tile k's 16-wave partial sum is reduced by wave 2
//    (P1-jobless) in region k+1, overlapping other waves' compute.
//
// CLOSED LINES (measured): explicit reg pipelining (v8/v12/v13 -> scratch
// or occupancy), occupancy reshaping (v9/v11), LDS atomics/setprio (v14),
// bank conflicts (v7), ws fill is unconditional (v7).
// ---------------------------------------------------------------------------

typedef __attribute__((ext_vector_type(8))) _Float16 f16x8;
typedef __attribute__((ext_vector_type(2))) __fp16   fp16v2;   // cvt_pkrtz ret
typedef __attribute__((ext_vector_type(4))) float    f32x4;
typedef __attribute__((ext_vector_type(4))) unsigned int u32x4;

constexpr int   BPT       = 16;       // batch elems per tile
constexpr int   NTILES    = 4;        // tiles per block (64 batch/block)
constexpr int   NT        = 1024;     // 16 waves
constexpr int   T_STRIDE  = 1664;     // 13 rows * 128 B, chunk-swizzled
constexpr int   TBUF      = BPT * T_STRIDE;       // 26624
constexpr int   PB_OFF    = 2 * TBUF;             // 53248: 2x [16][16] f32
constexpr int   LDS_BYTES = PB_OFF + 2048;        // 55296 -> 2 blocks/CU

// d_ws layout (bytes)
constexpr int   WS_W1F   = 0;         // 24576: f16 W1 in MFMA frag order
constexpr int   WS_W2T   = 24576;     //  4096: f16 [m=32][k=64]
constexpr int   WS_B1    = 28672;     //   256: f32 b1*L2E
constexpr int   WS_B2    = 28928;     //   128: f32 b2*L2E
constexpr int   WS_W3    = 29056;     //   128: f32 W3*LN2

constexpr float L2E = 1.4426950408889634f;
constexpr float LN2 = 0.6931471805599453f;

// PAIRS i/j packed 3 bits per pair (15 pairs)
constexpr unsigned long long I_BITS =
  (0ull<<0)|(0ull<<3)|(0ull<<6)|(0ull<<9)|(0ull<<12)|
  (1ull<<15)|(1ull<<18)|(1ull<<21)|(1ull<<24)|
  (2ull<<27)|(2ull<<30)|(2ull<<33)|
  (3ull<<36)|(3ull<<39)|(4ull<<42);
constexpr unsigned long long J_BITS =
  (1ull<<0)|(2ull<<3)|(3ull<<6)|(4ull<<9)|(5ull<<12)|
  (2ull<<15)|(3ull<<18)|(4ull<<21)|(5ull<<24)|
  (3ull<<27)|(4ull<<30)|(5ull<<33)|
  (4ull<<36)|(5ull<<39)|(5ull<<42);

__device__ __forceinline__ float sp2(float s) {       // log2(1+exp2(s))
  float t = __builtin_amdgcn_exp2f(s);
  return __builtin_amdgcn_logf(1.0f + t);             // v_log_f32 = log2
}

__device__ __forceinline__ __half2 h1pair(__half2 u, __half2 a, __half2 b,
                                          __half2 one2) {
  __half2 s = __hadd2(__hadd2(u, a), b);
  __half2 t = h2exp2(s);                              // |s|<~8 -> safe in f16
  return h2log2(__hadd2(one2, t));
}

// ------------------------- prep: weights -> d_ws ---------------------------
__global__ __launch_bounds__(256)
void prep(const float* __restrict__ W1, const float* __restrict__ b1,
          const float* __restrict__ W2, const float* __restrict__ b2,
          const float* __restrict__ W3, char* __restrict__ ws)
{
  const int t = (int)(blockIdx.x * blockDim.x + threadIdx.x);   // 0..14591
  if (t < 12288) {
    // W1F frag image, element t = sl*4096 + nt*1024 + ks*512 + qd*128 + ln*8 + e
    // value = W1[dg][n]*L2E with dg = sl*64+ks*32+qd*8+e, n = nt*16+ln.
    const int e  = t & 7;
    const int ln = (t >> 3) & 15;
    const int qd = (t >> 7) & 3;
    const int ks = (t >> 9) & 1;
    const int nt = (t >> 10) & 3;
    const int sl = t >> 12;
    const int dg = sl * 64 + ks * 32 + qd * 8 + e;
    const int n  = nt * 16 + ln;
    ((uint16_t*)(ws + WS_W1F))[t] =
        __half_as_ushort(__float2half(W1[(size_t)dg * 64 + n] * L2E));
  } else if (t < 14336) {
    const int e = t - 12288;                          // W2 is [k=64][m=32]
    const int k = e >> 5, m = e & 31;
    *(uint16_t*)(ws + WS_W2T + (m * 64 + k) * 2) =
        __half_as_ushort(__float2half(W2[e]));
  } else if (t < 14400) {
    ((float*)(ws + WS_B1))[t - 14336] = b1[t - 14336] * L2E;
  } else if (t < 14432) {
    ((float*)(ws + WS_B2))[t - 14400] = b2[t - 14400] * L2E;
  } else if (t < 14464) {
    ((float*)(ws + WS_W3))[t - 14432] = W3[t - 14432] * LN2;
  }
}

// ---------------- phase-2 unit macro (loop-local state) --------------------
#define P2_UNIT(Q_)                                                          \
  {                                                                          \
    const int p_  = (Q_) >> 1;                                               \
    const int iv_ = (int)((I_BITS >> (3 * p_)) & 7ull);                      \
    const int jv_ = (int)((J_BITS >> (3 * p_)) & 7ull);                      \
    const int An_ = ((Q_) & 1) ? jv_ : iv_;                                  \
    const int Bn_ = ((Q_) & 1) ? iv_ : jv_;                                  \
    const char* TA_ = Tb + (1 + An_) * 128;                                  \
    const char* TB_ = Tb + (7 + Bn_) * 128;                                  \
    U4 da0_, db0_, da1_, db1_;                                               \
    da0_.u = *(const u32x4*)(TA_ + k0);                                      \
    db0_.u = *(const u32x4*)(TB_ + k0);                                      \
    da1_.u = *(const u32x4*)(TA_ + k1);                                      \
    db1_.u = *(const u32x4*)(TB_ + k1);                                      \
    union AH_ { f16x8 v; __half2 h[4]; } A0_, A1_;                           \
    A0_.h[0] = h1pair(du0.h[0], da0_.h[0], db0_.h[0], one2);                 \
    A0_.h[1] = h1pair(du0.h[1], da0_.h[1], db0_.h[1], one2);                 \
    A0_.h[2] = h1pair(du0.h[2], da0_.h[2], db0_.h[2], one2);                 \
    A0_.h[3] = h1pair(du0.h[3], da0_.h[3], db0_.h[3], one2);                 \
    A1_.h[0] = h1pair(du1.h[0], da1_.h[0], db1_.h[0], one2);                 \
    A1_.h[1] = h1pair(du1.h[1], da1_.h[1], db1_.h[1], one2);                 \
    A1_.h[2] = h1pair(du1.h[2], da1_.h[2], db1_.h[2], one2);                 \
    A1_.h[3] = h1pair(du1.h[3], da1_.h[3], db1_.h[3], one2);                 \
    f32x4 c0_ = {b2v0, b2v0, b2v0, b2v0};                                    \
    f32x4 c1_ = {b2v1, b2v1, b2v1, b2v1};                                    \
    c0_ = __builtin_amdgcn_mfma_f32_16x16x32_f16(A0_.v, W2f[0][0], c0_, 0, 0, 0); \
    c0_ = __builtin_amdgcn_mfma_f32_16x16x32_f16(A1_.v, W2f[0][1], c0_, 0, 0, 0); \
    c1_ = __builtin_amdgcn_mfma_f32_16x16x32_f16(A0_.v, W2f[1][0], c1_, 0, 0, 0); \
    c1_ = __builtin_amdgcn_mfma_f32_16x16x32_f16(A1_.v, W2f[1][1], c1_, 0, 0, 0); \
    yacc0 += sp2(c0_[0]) * w3v0 + sp2(c1_[0]) * w3v1;                        \
    yacc1 += sp2(c0_[1]) * w3v0 + sp2(c1_[1]) * w3v1;                        \
    yacc2 += sp2(c0_[2]) * w3v0 + sp2(c1_[2]) * w3v1;                        \
    yacc3 += sp2(c0_[3]) * w3v0 + sp2(c1_[3]) * w3v1;                        \
  }

// ------------------------------ main kernel --------------------------------
__global__ __launch_bounds__(NT, 8)
void tb_fused(const float* __restrict__ core, const float* __restrict__ ligs,
              const char* __restrict__ ws,   const float* __restrict__ b3,
              float* __restrict__ out)
{
  extern __shared__ char smem[];
  const int tid  = (int)threadIdx.x;
  const int lane = tid & 63;
  const int ln   = lane & 15;        // fragment column
  const int qd   = lane >> 4;        // fragment quad
  const int swz  = ln & 7;           // XOR chunk swizzle key
  const int wv   = __builtin_amdgcn_readfirstlane(tid >> 6);  // 0..15
  const int b0   = (int)blockIdx.x * (BPT * NTILES);

  const int k0 = ((qd)     ^ swz) << 4;               // T chunk qd   (ks=0)
  const int k1 = ((qd + 4) ^ swz) << 4;               // T chunk qd+4 (ks=1)
  const __half2 one2 = __float2half2_rn(1.0f);
  union U4 { u32x4 u; __half2 h[4]; };

  const float b3v = b3[0];

  // P1 job assignment: waves 3..15 own T-row t = wv-3 (0=core, 1..6 slab1,
  // 7..12 slab2). P2: wave w owns units q=w and q=w+16 (if w<14).
  const bool haveJob = (wv >= 3);
  const int  jt      = wv - 3;
  const int  jsl     = (jt == 0) ? 0 : (jt <= 6 ? 1 : 2);
  const int  jlig    = (jt <= 6) ? (jt - 1) : (jt - 7);

  // W2 B-frags + epilogue consts from ws (pre-converted, L2-hot).
  f16x8 W2f[2][2];
  #pragma unroll
  for (int nt = 0; nt < 2; ++nt)
    #pragma unroll
    for (int ks = 0; ks < 2; ++ks)
      W2f[nt][ks] = *(const f16x8*)(ws + WS_W2T
          + ((nt * 16 + ln) * 64 + ks * 32 + qd * 8) * 2);
  const float b2v0 = ((const float*)(ws + WS_B2))[ln];
  const float b2v1 = ((const float*)(ws + WS_B2))[16 + ln];
  const float w3v0 = ((const float*)(ws + WS_W3))[ln];
  const float w3v1 = ((const float*)(ws + WS_W3))[16 + ln];

  // ---------------- prologue: P1(tile 0) into buffer 0 --------------------
  {
    float4 fA[4];
    if (haveJob) {
      const int bb = b0 + ln;                         // tile 0
      const float* src = (jt == 0)
          ? (core + (size_t)bb * 64)
          : (ligs + ((size_t)bb * 6 + (size_t)jlig) * 64);
      #pragma unroll
      for (int ks = 0; ks < 2; ++ks) {
        fA[ks * 2 + 0] = *(const float4*)(src + ks * 32 + qd * 8);
        fA[ks * 2 + 1] = *(const float4*)(src + ks * 32 + qd * 8 + 4);
      }
      union AFr { f16x8 v; fp16v2 p[4]; } Xf[2];
      #pragma unroll
      for (int ks = 0; ks < 2; ++ks) {
        Xf[ks].p[0] = __builtin_amdgcn_cvt_pkrtz(fA[ks*2].x, fA[ks*2].y);
        Xf[ks].p[1] = __builtin_amdgcn_cvt_pkrtz(fA[ks*2].z, fA[ks*2].w);
        Xf[ks].p[2] = __builtin_amdgcn_cvt_pkrtz(fA[ks*2+1].x, fA[ks*2+1].y);
        Xf[ks].p[3] = __builtin_amdgcn_cvt_pkrtz(fA[ks*2+1].z, fA[ks*2+1].w);
      }
      char* Tn = smem + (size_t)ln * T_STRIDE;        // buffer 0
      #pragma unroll
      for (int nt = 0; nt < 4; ++nt) {
        f32x4 c;
        if (jt == 0) c = *(const f32x4*)(ws + WS_B1 + (nt * 16 + qd * 4) * 4);
        else         c = (f32x4){0.f, 0.f, 0.f, 0.f};
        #pragma unroll
        for (int ks = 0; ks < 2; ++ks) {
          const f16x8 Wf = *(const f16x8*)(ws + WS_W1F
              + (size_t)(jsl * 4096 + nt * 1024 + ks * 512 + qd * 128 + ln * 8) * 2);
          c = __builtin_amdgcn_mfma_f32_16x16x32_f16(Wf, Xf[ks].v, c, 0, 0, 0);
        }
        union PK { uint2 u; __half2 h[2]; } pk;
        pk.h[0] = __halves2half2(__float2half(c[0]), __float2half(c[1]));
        pk.h[1] = __halves2half2(__float2half(c[2]), __float2half(c[3]));
        *(uint2*)(Tn + jt * 128
                  + ((((nt << 1) + (qd >> 1)) ^ swz) << 4) + (qd & 1) * 8) = pk.u;
      }
    }
  }
  __syncthreads();                                    // T(tile0) ready

  // ---------------- main: 4 merged regions --------------------------------
  #pragma unroll
  for (int k = 0; k < NTILES; ++k) {
    const char* Tb = smem + (size_t)(k & 1) * TBUF + (size_t)ln * T_STRIDE;

    // deferred output for tile k-1 (wave 2 has no P1 job)
    if (k > 0 && wv == 2 && lane < 16) {
      const float* pp = (const float*)(smem + PB_OFF + ((k - 1) & 1) * 1024);
      float s = 0.f;
      #pragma unroll
      for (int w = 0; w < 16; ++w) s += pp[w * 16 + lane];
      out[b0 + (k - 1) * 16 + lane] = 0.5f * s + 15.0f * b3v;
    }

    // x-loads for tile k+1: issue early, ~2 P2 units of latency cover
    float4 fA[4];
    if (k < NTILES - 1 && haveJob) {
      const int bb = b0 + (k + 1) * 16 + ln;
      const float* src = (jt == 0)
          ? (core + (size_t)bb * 64)
          : (ligs + ((size_t)bb * 6 + (size_t)jlig) * 64);
      #pragma unroll
      for (int ks = 0; ks < 2; ++ks) {
        fA[ks * 2 + 0] = *(const float4*)(src + ks * 32 + qd * 8);
        fA[ks * 2 + 1] = *(const float4*)(src + ks * 32 + qd * 8 + 4);
      }
    }

    // ---- P2(tile k): units q=wv and q=wv+16 ----
    U4 du0, du1;                                      // row 0 (core), hoisted
    du0.u = *(const u32x4*)(Tb + k0);
    du1.u = *(const u32x4*)(Tb + k1);
    float yacc0 = 0.f, yacc1 = 0.f, yacc2 = 0.f, yacc3 = 0.f;
    P2_UNIT(wv)
    if (wv < 14) { P2_UNIT(wv + 16) }

    // reduce over the 16 fragment columns (ln) inside each quad group
    yacc0 += __shfl_xor(yacc0, 1); yacc1 += __shfl_xor(yacc1, 1);
    yacc2 += __shfl_xor(yacc2, 1); yacc3 += __shfl_xor(yacc3, 1);
    yacc0 += __shfl_xor(yacc0, 2); yacc1 += __shfl_xor(yacc1, 2);
    yacc2 += __shfl_xor(yacc2, 2); yacc3 += __shfl_xor(yacc3, 2);
    yacc0 += __shfl_xor(yacc0, 4); yacc1 += __shfl_xor(yacc1, 4);
    yacc2 += __shfl_xor(yacc2, 4); yacc3 += __shfl_xor(yacc3, 4);
    yacc0 += __shfl_xor(yacc0, 8); yacc1 += __shfl_xor(yacc1, 8);
    yacc2 += __shfl_xor(yacc2, 8); yacc3 += __shfl_xor(yacc3, 8);
    if (ln == 0) {
      float* pb = (float*)(smem + PB_OFF + (k & 1) * 1024);
      *(f32x4*)(pb + wv * 16 + qd * 4) = (f32x4){yacc0, yacc1, yacc2, yacc3};
    }

    // ---- P1(tile k+1) into buffer (k+1)&1 ----
    if (k < NTILES - 1 && haveJob) {
      union AFr { f16x8 v; fp16v2 p[4]; } Xf[2];
      #pragma unroll
      for (int ks = 0; ks < 2; ++ks) {
        Xf[ks].p[0] = __builtin_amdgcn_cvt_pkrtz(fA[ks*2].x, fA[ks*2].y);
        Xf[ks].p[1] = __builtin_amdgcn_cvt_pkrtz(fA[ks*2].z, fA[ks*2].w);
        Xf[ks].p[2] = __builtin_amdgcn_cvt_pkrtz(fA[ks*2+1].x, fA[ks*2+1].y);
        Xf[ks].p[3] = __builtin_amdgcn_cvt_pkrtz(fA[ks*2+1].z, fA[ks*2+1].w);
      }
      char* Tn = smem + (size_t)((k + 1) & 1) * TBUF + (size_t)ln * T_STRIDE;
      #pragma unroll
      for (int nt = 0; nt < 4; ++nt) {
        f32x4 c;
        if (jt == 0) c = *(const f32x4*)(ws + WS_B1 + (nt * 16 + qd * 4) * 4);
        else         c = (f32x4){0.f, 0.f, 0.f, 0.f};
        #pragma unroll
        for (int ks = 0; ks < 2; ++ks) {
          const f16x8 Wf = *(const f16x8*)(ws + WS_W1F
              + (size_t)(jsl * 4096 + nt * 1024 + ks * 512 + qd * 128 + ln * 8) * 2);
          c = __builtin_amdgcn_mfma_f32_16x16x32_f16(Wf, Xf[ks].v, c, 0, 0, 0);
        }
        union PK { uint2 u; __half2 h[2]; } pk;
        pk.h[0] = __halves2half2(__float2half(c[0]), __float2half(c[1]));
        pk.h[1] = __halves2half2(__float2half(c[2]), __float2half(c[3]));
        *(uint2*)(Tn + jt * 128
                  + ((((nt << 1) + (qd >> 1)) ^ swz) << 4) + (qd & 1) * 8) = pk.u;
      }
    }

    __syncthreads();                                  // T(k+1) + partials(k)
  }

  // final output for tile NTILES-1
  if (wv == 2 && lane < 16) {
    const float* pp = (const float*)(smem + PB_OFF + ((NTILES - 1) & 1) * 1024);
    float s = 0.f;
    #pragma unroll
    for (int w = 0; w < 16; ++w) s += pp[w * 16 + lane];
    out[b0 + (NTILES - 1) * 16 + lane] = 0.5f * s + 15.0f * b3v;
  }
}

extern "C" void kernel_launch(void* const* d_in, const int* in_sizes, int n_in,
                              void* d_out, int out_size, void* d_ws, size_t ws_size,
                              hipStream_t stream) {
  const float* core = (const float*)d_in[0];
  const float* ligs = (const float*)d_in[1];
  const float* W1   = (const float*)d_in[2];
  const float* b1   = (const float*)d_in[3];
  const float* W2   = (const float*)d_in[4];
  const float* b2   = (const float*)d_in[5];
  const float* W3   = (const float*)d_in[6];
  const float* b3   = (const float*)d_in[7];
  float* out = (float*)d_out;
  char*  ws  = (char*)d_ws;                 // 29 KB used; fill is sunk cost

  const int B = in_sizes[0] / 64;           // 32768
  const int grid = B / (BPT * NTILES);      // 512 -> all blocks resident

  prep<<<dim3(57), dim3(256), 0, stream>>>(W1, b1, W2, b2, W3, ws);

  (void)hipFuncSetAttribute((const void*)tb_fused,
                            hipFuncAttributeMaxDynamicSharedMemorySize, LDS_BYTES);
  tb_fused<<<dim3(grid), dim3(NT), LDS_BYTES, stream>>>(
      core, ligs, ws, b3, out);
}

// Round 10
// 150.101 us; speedup vs baseline: 1.4358x; 1.4358x over previous
//
#include <hip/hip_runtime.h>
#include <hip/hip_fp16.h>
#include <stdint.h>

// ---------------------------------------------------------------------------
// ThreeBodyLayer fused kernel v16 (MI355X / gfx950)
//
// All-f16 MFMA pipeline, log2-domain softplus. Scale algebra: W1/b1 carry
// log2(e); W2 carries ln2*log2(e)=1; b2*L2E; W3*LN2.
//
// v16 = v10 (best measured 42.0-43.8us) with phase-2 rewritten UNION-FREE:
//  - Every union {vec; __half2[]} replaced by pure SSA __builtin_bit_cast;
//    no address-taken locals, no conditionally-written state. Hypothesis
//    (from v8/v13/v15 spills at VGPR=32 despite 64-reg budget): the union
//    pattern defeats SROA and pins values to memory, which both caused the
//    pipeline spills AND pins v10's allocation at 32 regs, preventing the
//    list scheduler from interleaving adjacent unit bodies.
//  - Phase-2 fully unrolled: units q=qr, qr+8, qr+16 straight-line in ONE
//    basic block (scheduler may interleave them freely), + wave-uniform
//    tail body (qr<6). No explicit pipelining (closed line); we only give
//    the compiler SSA form + headroom and let it schedule.
//  - Everything else byte-identical to v10: BPB=32/NT=1024/78KB LDS,
//    pre-swizzled W1T image copy, operand-swapped P1 + packed b64 C-writes,
//    b1/b2-in-C-init, W2/b2/w3 from ws, du-hoist, chunk swizzle, RNE cvt.
//
// CLOSED LINES (measured): explicit reg pipelining (v8/v12/v13), phase-
// merged tiles (v15), occupancy reshaping (v9/v11), atomic-free tail +
// setprio (v14 neutral), W1-from-L2 without LDS (v11 -2us), bank conflicts
// (v7 null), ws fill unconditional (v7).
// ---------------------------------------------------------------------------

typedef __attribute__((ext_vector_type(8))) _Float16 f16x8;
typedef __attribute__((ext_vector_type(2))) __fp16   fp16v2;   // cvt_pkrtz ret
typedef __attribute__((ext_vector_type(4))) float    f32x4;
typedef __attribute__((ext_vector_type(4))) unsigned int u32x4;

constexpr int   BPB       = 32;       // batch elems per block
constexpr int   NT        = 1024;     // 16 waves
constexpr int   T_STRIDE  = 1664;     // 13 rows * 128 B, chunk-swizzled
constexpr int   WT_OFF    = BPB * T_STRIDE;       // 53248
constexpr int   Y_OFF     = WT_OFF + 192 * 128;   // 77824
constexpr int   LDS_BYTES = Y_OFF + 128;          // 77952 -> 2 blocks/CU

// d_ws layout (bytes)
constexpr int   WS_W1T   = 0;         // 24576: f16 LDS image (pre-swizzled)
constexpr int   WS_W2T   = 24576;     //  4096: f16 [m=32][k=64]
constexpr int   WS_B1    = 28672;     //   256: f32 b1*L2E
constexpr int   WS_B2    = 28928;     //   128: f32 b2*L2E
constexpr int   WS_W3    = 29056;     //   128: f32 W3*LN2

constexpr float L2E = 1.4426950408889634f;
constexpr float LN2 = 0.6931471805599453f;

// PAIRS i/j packed 3 bits per pair (15 pairs)
constexpr unsigned long long I_BITS =
  (0ull<<0)|(0ull<<3)|(0ull<<6)|(0ull<<9)|(0ull<<12)|
  (1ull<<15)|(1ull<<18)|(1ull<<21)|(1ull<<24)|
  (2ull<<27)|(2ull<<30)|(2ull<<33)|
  (3ull<<36)|(3ull<<39)|(4ull<<42);
constexpr unsigned long long J_BITS =
  (1ull<<0)|(2ull<<3)|(3ull<<6)|(4ull<<9)|(5ull<<12)|
  (2ull<<15)|(3ull<<18)|(4ull<<21)|(5ull<<24)|
  (3ull<<27)|(4ull<<30)|(5ull<<33)|
  (4ull<<36)|(5ull<<39)|(5ull<<42);

__device__ __forceinline__ float sp2(float s) {       // log2(1+exp2(s))
  float t = __builtin_amdgcn_exp2f(s);
  return __builtin_amdgcn_logf(1.0f + t);             // v_log_f32 = log2
}

__device__ __forceinline__ __half2 h1pair(__half2 u, __half2 a, __half2 b,
                                          __half2 one2) {
  __half2 s = __hadd2(__hadd2(u, a), b);
  __half2 t = h2exp2(s);                              // |s|<~8 -> safe in f16
  return h2log2(__hadd2(one2, t));
}

#define BCH(x) __builtin_bit_cast(__half2, (unsigned int)(x))
#define BCU(x) __builtin_bit_cast(unsigned int, (x))

// ------------------------- prep: weights -> d_ws ---------------------------
__global__ __launch_bounds__(256)
void prep(const float* __restrict__ W1, const float* __restrict__ b1,
          const float* __restrict__ W2, const float* __restrict__ b2,
          const float* __restrict__ W3, char* __restrict__ ws)
{
  const int t = (int)(blockIdx.x * blockDim.x + threadIdx.x);   // 0..14591
  if (t < 12288) {
    // W1T LDS image: row r = slab*64+n (128B), logical d-chunk dc stored at
    // chunk dc^(r&7); element (r, dl): dg = slab*64+dl, value W1[dg][n]*L2E.
    const int r = t >> 6, dl = t & 63;
    const int slab = r >> 6, n = r & 63;
    const int dg = slab * 64 + dl;
    const float v = W1[(size_t)dg * 64 + n] * L2E;
    *(uint16_t*)(ws + WS_W1T + r * 128 + (((dl >> 3) ^ (r & 7)) << 4)
                 + (dl & 7) * 2) = __half_as_ushort(__float2half(v));
  } else if (t < 14336) {
    const int e = t - 12288;                          // W2 is [k=64][m=32]
    const int k = e >> 5, m = e & 31;
    *(uint16_t*)(ws + WS_W2T + (m * 64 + k) * 2) =
        __half_as_ushort(__float2half(W2[e]));
  } else if (t < 14400) {
    ((float*)(ws + WS_B1))[t - 14336] = b1[t - 14336] * L2E;
  } else if (t < 14432) {
    ((float*)(ws + WS_B2))[t - 14400] = b2[t - 14400] * L2E;
  } else if (t < 14464) {
    ((float*)(ws + WS_W3))[t - 14432] = W3[t - 14432] * LN2;
  }
}

// ---------------- phase-2 unit macro: pure SSA, block-local ---------------
#define P2U(Q_)                                                              \
  {                                                                          \
    const int p_  = (Q_) >> 1;                                               \
    const int iv_ = (int)((I_BITS >> (3 * p_)) & 7ull);                      \
    const int jv_ = (int)((J_BITS >> (3 * p_)) & 7ull);                      \
    const int An_ = ((Q_) & 1) ? jv_ : iv_;                                  \
    const int Bn_ = ((Q_) & 1) ? iv_ : jv_;                                  \
    const char* TA_ = Tb + (1 + An_) * 128;                                  \
    const char* TB_ = Tb + (7 + Bn_) * 128;                                  \
    const u32x4 da0_ = *(const u32x4*)(TA_ + k0);                            \
    const u32x4 db0_ = *(const u32x4*)(TB_ + k0);                            \
    const u32x4 da1_ = *(const u32x4*)(TA_ + k1);                            \
    const u32x4 db1_ = *(const u32x4*)(TB_ + k1);                            \
    u32x4 A0u_, A1u_;                                                        \
    A0u_[0] = BCU(h1pair(BCH(du0[0]), BCH(da0_[0]), BCH(db0_[0]), one2));    \
    A0u_[1] = BCU(h1pair(BCH(du0[1]), BCH(da0_[1]), BCH(db0_[1]), one2));    \
    A0u_[2] = BCU(h1pair(BCH(du0[2]), BCH(da0_[2]), BCH(db0_[2]), one2));    \
    A0u_[3] = BCU(h1pair(BCH(du0[3]), BCH(da0_[3]), BCH(db0_[3]), one2));    \
    A1u_[0] = BCU(h1pair(BCH(du1[0]), BCH(da1_[0]), BCH(db1_[0]), one2));    \
    A1u_[1] = BCU(h1pair(BCH(du1[1]), BCH(da1_[1]), BCH(db1_[1]), one2));    \
    A1u_[2] = BCU(h1pair(BCH(du1[2]), BCH(da1_[2]), BCH(db1_[2]), one2));    \
    A1u_[3] = BCU(h1pair(BCH(du1[3]), BCH(da1_[3]), BCH(db1_[3]), one2));    \
    const f16x8 A0_ = __builtin_bit_cast(f16x8, A0u_);                       \
    const f16x8 A1_ = __builtin_bit_cast(f16x8, A1u_);                       \
    f32x4 c0_ = {b2v0, b2v0, b2v0, b2v0};                                    \
    f32x4 c1_ = {b2v1, b2v1, b2v1, b2v1};                                    \
    c0_ = __builtin_amdgcn_mfma_f32_16x16x32_f16(A0_, W2f00, c0_, 0, 0, 0);  \
    c0_ = __builtin_amdgcn_mfma_f32_16x16x32_f16(A1_, W2f01, c0_, 0, 0, 0);  \
    c1_ = __builtin_amdgcn_mfma_f32_16x16x32_f16(A0_, W2f10, c1_, 0, 0, 0);  \
    c1_ = __builtin_amdgcn_mfma_f32_16x16x32_f16(A1_, W2f11, c1_, 0, 0, 0);  \
    yacc0 += sp2(c0_[0]) * w3v0 + sp2(c1_[0]) * w3v1;                        \
    yacc1 += sp2(c0_[1]) * w3v0 + sp2(c1_[1]) * w3v1;                        \
    yacc2 += sp2(c0_[2]) * w3v0 + sp2(c1_[2]) * w3v1;                        \
    yacc3 += sp2(c0_[3]) * w3v0 + sp2(c1_[3]) * w3v1;                        \
  }

// ------------------------------ main kernel --------------------------------
__global__ __launch_bounds__(NT, 8)
void tb_fused(const float* __restrict__ core, const float* __restrict__ ligs,
              const char* __restrict__ ws,   const float* __restrict__ b3,
              float* __restrict__ out)
{
  extern __shared__ char smem[];
  const int tid  = (int)threadIdx.x;
  const int lane = tid & 63;
  const int ln   = lane & 15;        // fragment column
  const int qd   = lane >> 4;        // fragment quad
  const int swz  = ln & 7;           // XOR chunk swizzle key
  const int wv   = __builtin_amdgcn_readfirstlane(tid >> 6);  // 0..15
  const int b0   = (int)blockIdx.x * BPB;

  float* yred = (float*)(smem + Y_OFF);

  // ---- Phase-1 x-tile prefetch (cold HBM): issue before LDS staging ------
  const int xr = wv >> 1;
  const int mt = wv & 1;
  float4 fA[4];
  if (wv < 14) {
    const float* src = (xr == 0)
        ? (core + (size_t)(b0 + mt * 16 + ln) * 64)
        : (ligs + ((size_t)(b0 + mt * 16 + ln) * 6 + (size_t)(xr - 1)) * 64);
    #pragma unroll
    for (int ks = 0; ks < 2; ++ks) {
      fA[ks * 2 + 0] = *(const float4*)(src + ks * 32 + qd * 8);
      fA[ks * 2 + 1] = *(const float4*)(src + ks * 32 + qd * 8 + 4);
    }
  }

  // ---- stage W1T: plain vector copy of the pre-swizzled f16 image --------
  {
    const uint4* src = (const uint4*)(ws + WS_W1T);   // 1536 chunks of 16B
    uint4*       dst = (uint4*)(smem + WT_OFF);
    dst[tid] = src[tid];
    if (tid < 512) dst[1024 + tid] = src[1024 + tid];
  }
  if (tid < BPB) yred[tid] = 0.0f;
  __syncthreads();                                    // barrier #1: W1T ready

  // ------------- Phase 1: 14 jobs = (xr 0..6) x (mt 0..1), 1 per wave -----
  if (wv < 14) {
    union AFr { f16x8 v; fp16v2 p[4]; } Xf[2];        // x frags (B operand)
    #pragma unroll
    for (int ks = 0; ks < 2; ++ks) {
      Xf[ks].p[0] = __builtin_amdgcn_cvt_pkrtz(fA[ks*2].x, fA[ks*2].y);
      Xf[ks].p[1] = __builtin_amdgcn_cvt_pkrtz(fA[ks*2].z, fA[ks*2].w);
      Xf[ks].p[2] = __builtin_amdgcn_cvt_pkrtz(fA[ks*2+1].x, fA[ks*2+1].y);
      Xf[ks].p[3] = __builtin_amdgcn_cvt_pkrtz(fA[ks*2+1].z, fA[ks*2+1].w);
    }

    const int sl_lo = (xr == 0) ? 0 : 1;
    const int sl_hi = (xr == 0) ? 0 : 2;
    #pragma unroll 1
    for (int sl = sl_lo; sl <= sl_hi; ++sl) {
      const int trow = (xr == 0) ? 0 : ((sl == 1) ? xr : 6 + xr);
      #pragma unroll
      for (int nt = 0; nt < 4; ++nt) {
        // D row = n (H1), col = batch: bias b1 folds into C-init (t=0 only).
        f32x4 c;
        if (trow == 0) {
          c = *(const f32x4*)(ws + WS_B1 + (nt * 16 + qd * 4) * 4);
        } else {
          c = (f32x4){0.f, 0.f, 0.f, 0.f};
        }
        #pragma unroll
        for (int ks = 0; ks < 2; ++ks) {
          // A = W1T frag: row = sl*64+nt*16+ln (row&7 == swz), chunk ks*4+qd
          const f16x8 Wf = *(const f16x8*)(smem + WT_OFF
              + (sl * 64 + nt * 16 + ln) * 128 + ((((ks << 2) + qd) ^ swz) << 4));
          c = __builtin_amdgcn_mfma_f32_16x16x32_f16(Wf, Xf[ks].v, c, 0, 0, 0);
        }
        // c[0..3] = consecutive n = nt*16+qd*4+reg, batch b = mt*16+ln.
        // One b64 write: off = trow*128 + ((2nt+(qd>>1))^(b&7))*16 + (qd&1)*8
        union PK { uint2 u; __half2 h[2]; } pk;
        pk.h[0] = __halves2half2(__float2half(c[0]), __float2half(c[1]));
        pk.h[1] = __halves2half2(__float2half(c[2]), __float2half(c[3]));
        *(uint2*)(smem + (size_t)(mt * 16 + ln) * T_STRIDE + trow * 128
                  + ((((nt << 1) + (qd >> 1)) ^ swz) << 4) + (qd & 1) * 8) = pk.u;
      }
    }
  }

  // W2 B-frags + epilogue consts from ws (pre-converted, L2-hot) —
  // overlaps Phase-1 tail.
  const f16x8 W2f00 = *(const f16x8*)(ws + WS_W2T + ((0 * 16 + ln) * 64 + 0 * 32 + qd * 8) * 2);
  const f16x8 W2f01 = *(const f16x8*)(ws + WS_W2T + ((0 * 16 + ln) * 64 + 1 * 32 + qd * 8) * 2);
  const f16x8 W2f10 = *(const f16x8*)(ws + WS_W2T + ((1 * 16 + ln) * 64 + 0 * 32 + qd * 8) * 2);
  const f16x8 W2f11 = *(const f16x8*)(ws + WS_W2T + ((1 * 16 + ln) * 64 + 1 * 32 + qd * 8) * 2);
  const float b2v0 = ((const float*)(ws + WS_B2))[ln];
  const float b2v1 = ((const float*)(ws + WS_B2))[16 + ln];
  const float w3v0 = ((const float*)(ws + WS_W3))[ln];
  const float w3v1 = ((const float*)(ws + WS_W3))[16 + ln];

  __syncthreads();                                    // barrier #2: T ready

  // ------------- Phase 2: 60 units (30 q x 2 mt) over 16 waves ------------
  const int mtw = wv & 1;
  const int qr  = wv >> 1;                            // 0..7
  const __half2 one2 = __float2half2_rn(1.0f);
  const char* Tb = smem + (size_t)(mtw * 16 + ln) * T_STRIDE;
  const int k0 = ((qd)     ^ swz) << 4;               // chunk qd   (ks=0)
  const int k1 = ((qd + 4) ^ swz) << 4;               // chunk qd+4 (ks=1)

  // Row 0 (core pre-activations) is unit-invariant: hoist its 2 reads.
  const u32x4 du0 = *(const u32x4*)(Tb + k0);
  const u32x4 du1 = *(const u32x4*)(Tb + k1);

  float yacc0 = 0.f, yacc1 = 0.f, yacc2 = 0.f, yacc3 = 0.f;

  // Straight-line: 3 unconditional units in one basic block, + uniform tail.
  P2U(qr)
  P2U(qr + 8)
  P2U(qr + 16)
  if (qr < 6) {                                       // wave-uniform
    P2U(qr + 24)
  }

  // reduce over the 16 fragment columns (ln) inside each quad group
  yacc0 += __shfl_xor(yacc0, 1); yacc1 += __shfl_xor(yacc1, 1);
  yacc2 += __shfl_xor(yacc2, 1); yacc3 += __shfl_xor(yacc3, 1);
  yacc0 += __shfl_xor(yacc0, 2); yacc1 += __shfl_xor(yacc1, 2);
  yacc2 += __shfl_xor(yacc2, 2); yacc3 += __shfl_xor(yacc3, 2);
  yacc0 += __shfl_xor(yacc0, 4); yacc1 += __shfl_xor(yacc1, 4);
  yacc2 += __shfl_xor(yacc2, 4); yacc3 += __shfl_xor(yacc3, 4);
  yacc0 += __shfl_xor(yacc0, 8); yacc1 += __shfl_xor(yacc1, 8);
  yacc2 += __shfl_xor(yacc2, 8); yacc3 += __shfl_xor(yacc3, 8);
  if (ln == 0) {
    atomicAdd(&yred[mtw * 16 + qd * 4 + 0], yacc0);
    atomicAdd(&yred[mtw * 16 + qd * 4 + 1], yacc1);
    atomicAdd(&yred[mtw * 16 + qd * 4 + 2], yacc2);
    atomicAdd(&yred[mtw * 16 + qd * 4 + 3], yacc3);
  }
  __syncthreads();
  if (tid < BPB) out[b0 + tid] = 0.5f * yred[tid] + 15.0f * b3[0];
}

extern "C" void kernel_launch(void* const* d_in, const int* in_sizes, int n_in,
                              void* d_out, int out_size, void* d_ws, size_t ws_size,
                              hipStream_t stream) {
  const float* core = (const float*)d_in[0];
  const float* ligs = (const float*)d_in[1];
  const float* W1   = (const float*)d_in[2];
  const float* b1   = (const float*)d_in[3];
  const float* W2   = (const float*)d_in[4];
  const float* b2   = (const float*)d_in[5];
  const float* W3   = (const float*)d_in[6];
  const float* b3   = (const float*)d_in[7];
  float* out = (float*)d_out;
  char*  ws  = (char*)d_ws;                 // 29 KB used; fill is sunk cost

  const int B = in_sizes[0] / 64;           // 32768
  const int grid = B / BPB;                 // 1024

  prep<<<dim3(57), dim3(256), 0, stream>>>(W1, b1, W2, b2, W3, ws);

  (void)hipFuncSetAttribute((const void*)tb_fused,
                            hipFuncAttributeMaxDynamicSharedMemorySize, LDS_BYTES);
  tb_fused<<<dim3(grid), dim3(NT), LDS_BYTES, stream>>>(
      core, ligs, ws, b3, out);
}

// Round 11
// 126.270 us; speedup vs baseline: 1.7068x; 1.1887x over previous
//
#include <hip/hip_runtime.h>
#include <hip/hip_fp16.h>
#include <stdint.h>

// ---------------------------------------------------------------------------
// ThreeBodyLayer fused kernel v17 == v10 (MI355X / gfx950) — RESTORATION
//
// All-f16 MFMA pipeline, log2-domain softplus. Scale algebra: W1/b1 carry
// log2(e); W2 carries ln2*log2(e)=1; b2*L2E; W3*LN2.
//
// v10 is the best-measured variant (tb_fused 42.0-43.8us, dur 126.28; two
// independent bench rounds). v16 (67us, spilled) is rolled back.
//
// SESSION VERDICT (v7-v16, all measured):
//  - Only real win: cutting overhead VALU (v10: ws-prepped weights, operand-
//    swapped P1 mfma(W1,x) -> packed b64 C-writes, b1/b2 in MFMA C-init).
//  - CLOSED: latency-hiding via live register state. FIVE formulations
//    (v8 helper-refs, v12 waves_per_eu+walls, v13 in-cap named sets,
//    v15 phase-merged tiles, v16 pure-SSA straight-line) all spill at
//    VGPR=32 or halve occupancy. This toolchain pins the kernel at ~32
//    VGPRs and will scratch-spill rather than widen; per-wave trans/LDS
//    dependency stalls (~50% issue-idle) are unreachable at source level.
//  - CLOSED: occupancy/block reshaping (v9/v11), bank conflicts (v7:
//    fixed 3.6x, zero time impact), atomic-free tail + setprio (v14 null),
//    W1-from-L2-no-LDS (v11: -2us).
//  - Not a HW roofline: HBM 8%, MfmaUtil 6%, VALUBusy ~47%. Issue-work
//    floor ~20us; binding constraint is compiler register allocation.
//  - dur_us carries a fixed ~84us harness overhead (256MiB ws re-poison
//    fill runs unconditionally — v7 proved it; using ws is free).
// ---------------------------------------------------------------------------

typedef __attribute__((ext_vector_type(8))) _Float16 f16x8;
typedef __attribute__((ext_vector_type(2))) __fp16   fp16v2;   // cvt_pkrtz ret
typedef __attribute__((ext_vector_type(4))) float    f32x4;
typedef __attribute__((ext_vector_type(4))) unsigned int u32x4;

constexpr int   BPB       = 32;       // batch elems per block
constexpr int   NT        = 1024;     // 16 waves
constexpr int   T_STRIDE  = 1664;     // 13 rows * 128 B, chunk-swizzled
constexpr int   WT_OFF    = BPB * T_STRIDE;       // 53248
constexpr int   Y_OFF     = WT_OFF + 192 * 128;   // 77824
constexpr int   LDS_BYTES = Y_OFF + 128;          // 77952 -> 2 blocks/CU

// d_ws layout (bytes)
constexpr int   WS_W1T   = 0;         // 24576: f16 LDS image (pre-swizzled)
constexpr int   WS_W2T   = 24576;     //  4096: f16 [m=32][k=64]
constexpr int   WS_B1    = 28672;     //   256: f32 b1*L2E
constexpr int   WS_B2    = 28928;     //   128: f32 b2*L2E
constexpr int   WS_W3    = 29056;     //   128: f32 W3*LN2

constexpr float L2E = 1.4426950408889634f;
constexpr float LN2 = 0.6931471805599453f;

// PAIRS i/j packed 3 bits per pair (15 pairs)
constexpr unsigned long long I_BITS =
  (0ull<<0)|(0ull<<3)|(0ull<<6)|(0ull<<9)|(0ull<<12)|
  (1ull<<15)|(1ull<<18)|(1ull<<21)|(1ull<<24)|
  (2ull<<27)|(2ull<<30)|(2ull<<33)|
  (3ull<<36)|(3ull<<39)|(4ull<<42);
constexpr unsigned long long J_BITS =
  (1ull<<0)|(2ull<<3)|(3ull<<6)|(4ull<<9)|(5ull<<12)|
  (2ull<<15)|(3ull<<18)|(4ull<<21)|(5ull<<24)|
  (3ull<<27)|(4ull<<30)|(5ull<<33)|
  (4ull<<36)|(5ull<<39)|(5ull<<42);

__device__ __forceinline__ float sp2(float s) {       // log2(1+exp2(s))
  float t = __builtin_amdgcn_exp2f(s);
  return __builtin_amdgcn_logf(1.0f + t);             // v_log_f32 = log2
}

__device__ __forceinline__ __half2 h1pair(__half2 u, __half2 a, __half2 b,
                                          __half2 one2) {
  __half2 s = __hadd2(__hadd2(u, a), b);
  __half2 t = h2exp2(s);                              // |s|<~8 -> safe in f16
  return h2log2(__hadd2(one2, t));
}

// ------------------------- prep: weights -> d_ws ---------------------------
__global__ __launch_bounds__(256)
void prep(const float* __restrict__ W1, const float* __restrict__ b1,
          const float* __restrict__ W2, const float* __restrict__ b2,
          const float* __restrict__ W3, char* __restrict__ ws)
{
  const int t = (int)(blockIdx.x * blockDim.x + threadIdx.x);   // 0..14591
  if (t < 12288) {
    // W1T LDS image: row r = slab*64+n (128B), logical d-chunk dc stored at
    // chunk dc^(r&7); element (r, dl): dg = slab*64+dl, value W1[dg][n]*L2E.
    const int r = t >> 6, dl = t & 63;
    const int slab = r >> 6, n = r & 63;
    const int dg = slab * 64 + dl;
    const float v = W1[(size_t)dg * 64 + n] * L2E;
    *(uint16_t*)(ws + WS_W1T + r * 128 + (((dl >> 3) ^ (r & 7)) << 4)
                 + (dl & 7) * 2) = __half_as_ushort(__float2half(v));
  } else if (t < 14336) {
    const int e = t - 12288;                          // W2 is [k=64][m=32]
    const int k = e >> 5, m = e & 31;
    *(uint16_t*)(ws + WS_W2T + (m * 64 + k) * 2) =
        __half_as_ushort(__float2half(W2[e]));
  } else if (t < 14400) {
    ((float*)(ws + WS_B1))[t - 14336] = b1[t - 14336] * L2E;
  } else if (t < 14432) {
    ((float*)(ws + WS_B2))[t - 14400] = b2[t - 14400] * L2E;
  } else if (t < 14464) {
    ((float*)(ws + WS_W3))[t - 14432] = W3[t - 14432] * LN2;
  }
}

// ------------------------------ main kernel --------------------------------
__global__ __launch_bounds__(NT, 8)
void tb_fused(const float* __restrict__ core, const float* __restrict__ ligs,
              const char* __restrict__ ws,   const float* __restrict__ b3,
              float* __restrict__ out)
{
  extern __shared__ char smem[];
  const int tid  = (int)threadIdx.x;
  const int lane = tid & 63;
  const int ln   = lane & 15;        // fragment column
  const int qd   = lane >> 4;        // fragment quad
  const int swz  = ln & 7;           // XOR chunk swizzle key
  const int wv   = __builtin_amdgcn_readfirstlane(tid >> 6);  // 0..15
  const int b0   = (int)blockIdx.x * BPB;

  float* yred = (float*)(smem + Y_OFF);

  // ---- Phase-1 x-tile prefetch (cold HBM): issue before LDS staging ------
  const int xr = wv >> 1;
  const int mt = wv & 1;
  float4 fA[4];
  if (wv < 14) {
    const float* src = (xr == 0)
        ? (core + (size_t)(b0 + mt * 16 + ln) * 64)
        : (ligs + ((size_t)(b0 + mt * 16 + ln) * 6 + (size_t)(xr - 1)) * 64);
    #pragma unroll
    for (int ks = 0; ks < 2; ++ks) {
      fA[ks * 2 + 0] = *(const float4*)(src + ks * 32 + qd * 8);
      fA[ks * 2 + 1] = *(const float4*)(src + ks * 32 + qd * 8 + 4);
    }
  }

  // ---- stage W1T: plain vector copy of the pre-swizzled f16 image --------
  {
    const uint4* src = (const uint4*)(ws + WS_W1T);   // 1536 chunks of 16B
    uint4*       dst = (uint4*)(smem + WT_OFF);
    dst[tid] = src[tid];
    if (tid < 512) dst[1024 + tid] = src[1024 + tid];
  }
  if (tid < BPB) yred[tid] = 0.0f;
  __syncthreads();                                    // barrier #1: W1T ready

  // ------------- Phase 1: 14 jobs = (xr 0..6) x (mt 0..1), 1 per wave -----
  if (wv < 14) {
    union AFr { f16x8 v; fp16v2 p[4]; } Xf[2];        // x frags (B operand)
    #pragma unroll
    for (int ks = 0; ks < 2; ++ks) {
      Xf[ks].p[0] = __builtin_amdgcn_cvt_pkrtz(fA[ks*2].x, fA[ks*2].y);
      Xf[ks].p[1] = __builtin_amdgcn_cvt_pkrtz(fA[ks*2].z, fA[ks*2].w);
      Xf[ks].p[2] = __builtin_amdgcn_cvt_pkrtz(fA[ks*2+1].x, fA[ks*2+1].y);
      Xf[ks].p[3] = __builtin_amdgcn_cvt_pkrtz(fA[ks*2+1].z, fA[ks*2+1].w);
    }

    const int sl_lo = (xr == 0) ? 0 : 1;
    const int sl_hi = (xr == 0) ? 0 : 2;
    #pragma unroll 1
    for (int sl = sl_lo; sl <= sl_hi; ++sl) {
      const int trow = (xr == 0) ? 0 : ((sl == 1) ? xr : 6 + xr);
      #pragma unroll
      for (int nt = 0; nt < 4; ++nt) {
        // D row = n (H1), col = batch: bias b1 folds into C-init (t=0 only).
        f32x4 c;
        if (trow == 0) {
          c = *(const f32x4*)(ws + WS_B1 + (nt * 16 + qd * 4) * 4);
        } else {
          c = (f32x4){0.f, 0.f, 0.f, 0.f};
        }
        #pragma unroll
        for (int ks = 0; ks < 2; ++ks) {
          // A = W1T frag: row = sl*64+nt*16+ln (row&7 == swz), chunk ks*4+qd
          const f16x8 Wf = *(const f16x8*)(smem + WT_OFF
              + (sl * 64 + nt * 16 + ln) * 128 + ((((ks << 2) + qd) ^ swz) << 4));
          c = __builtin_amdgcn_mfma_f32_16x16x32_f16(Wf, Xf[ks].v, c, 0, 0, 0);
        }
        // c[0..3] = consecutive n = nt*16+qd*4+reg, batch b = mt*16+ln.
        // One b64 write: off = trow*128 + ((2nt+(qd>>1))^(b&7))*16 + (qd&1)*8
        union PK { uint2 u; __half2 h[2]; } pk;
        pk.h[0] = __halves2half2(__float2half(c[0]), __float2half(c[1]));
        pk.h[1] = __halves2half2(__float2half(c[2]), __float2half(c[3]));
        *(uint2*)(smem + (size_t)(mt * 16 + ln) * T_STRIDE + trow * 128
                  + ((((nt << 1) + (qd >> 1)) ^ swz) << 4) + (qd & 1) * 8) = pk.u;
      }
    }
  }

  // W2 B-frags + epilogue consts from ws (pre-converted, L2-hot) —
  // overlaps Phase-1 tail.
  f16x8 W2f[2][2];
  #pragma unroll
  for (int nt = 0; nt < 2; ++nt)
    #pragma unroll
    for (int ks = 0; ks < 2; ++ks)
      W2f[nt][ks] = *(const f16x8*)(ws + WS_W2T
          + ((nt * 16 + ln) * 64 + ks * 32 + qd * 8) * 2);
  float b2v[2], w3v[2];
  #pragma unroll
  for (int nt = 0; nt < 2; ++nt) {
    b2v[nt] = ((const float*)(ws + WS_B2))[nt * 16 + ln];
    w3v[nt] = ((const float*)(ws + WS_W3))[nt * 16 + ln];
  }

  __syncthreads();                                    // barrier #2: T ready

  // ------------- Phase 2: 60 units (30 q x 2 mt) over 16 waves ------------
  const int mtw = wv & 1;
  const int qr  = wv >> 1;                            // 0..7
  const __half2 one2 = __float2half2_rn(1.0f);
  const char* Tb = smem + (size_t)(mtw * 16 + ln) * T_STRIDE;
  const int k0 = ((qd)     ^ swz) << 4;               // chunk qd   (ks=0)
  const int k1 = ((qd + 4) ^ swz) << 4;               // chunk qd+4 (ks=1)

  union U4 { u32x4 u; __half2 h[4]; };

  // Row 0 (core pre-activations) is unit-invariant: hoist its 2 reads.
  U4 du0, du1;
  du0.u = *(const u32x4*)(Tb + k0);
  du1.u = *(const u32x4*)(Tb + k1);

  float yacc[4] = {0.f, 0.f, 0.f, 0.f};

  #pragma unroll 2
  for (int t3 = 0; t3 < 4; ++t3) {
    const int q = qr + 8 * t3;
    if (q >= 30) break;                               // wave-uniform
    const int p  = q >> 1;
    const int iv = (int)((I_BITS >> (3 * p)) & 7ull);
    const int jv = (int)((J_BITS >> (3 * p)) & 7ull);
    const int An = (q & 1) ? jv : iv;
    const int Bn = (q & 1) ? iv : jv;
    const char* TA = Tb + (1 + An) * 128;
    const char* TB = Tb + (7 + Bn) * 128;

    U4 da0, db0, da1, db1;
    da0.u = *(const u32x4*)(TA + k0);
    db0.u = *(const u32x4*)(TB + k0);
    da1.u = *(const u32x4*)(TA + k1);
    db1.u = *(const u32x4*)(TB + k1);

    union { f16x8 v; __half2 h[4]; } A0, A1;
    #pragma unroll
    for (int w = 0; w < 4; ++w) A0.h[w] = h1pair(du0.h[w], da0.h[w], db0.h[w], one2);
    #pragma unroll
    for (int w = 0; w < 4; ++w) A1.h[w] = h1pair(du1.h[w], da1.h[w], db1.h[w], one2);

    f32x4 c0 = {b2v[0], b2v[0], b2v[0], b2v[0]};      // bias as C-init
    f32x4 c1 = {b2v[1], b2v[1], b2v[1], b2v[1]};
    c0 = __builtin_amdgcn_mfma_f32_16x16x32_f16(A0.v, W2f[0][0], c0, 0, 0, 0);
    c0 = __builtin_amdgcn_mfma_f32_16x16x32_f16(A1.v, W2f[0][1], c0, 0, 0, 0);
    c1 = __builtin_amdgcn_mfma_f32_16x16x32_f16(A0.v, W2f[1][0], c1, 0, 0, 0);
    c1 = __builtin_amdgcn_mfma_f32_16x16x32_f16(A1.v, W2f[1][1], c1, 0, 0, 0);

    #pragma unroll
    for (int reg = 0; reg < 4; ++reg) {
      yacc[reg] += sp2(c0[reg]) * w3v[0] + sp2(c1[reg]) * w3v[1];
    }
  }

  // reduce over the 16 fragment columns (ln) inside each quad group
  #pragma unroll
  for (int reg = 0; reg < 4; ++reg) {
    float v = yacc[reg];
    v += __shfl_xor(v, 1);
    v += __shfl_xor(v, 2);
    v += __shfl_xor(v, 4);
    v += __shfl_xor(v, 8);
    yacc[reg] = v;
  }
  if (ln == 0) {
    #pragma unroll
    for (int reg = 0; reg < 4; ++reg)
      atomicAdd(&yred[mtw * 16 + qd * 4 + reg], yacc[reg]);
  }
  __syncthreads();
  if (tid < BPB) out[b0 + tid] = 0.5f * yred[tid] + 15.0f * b3[0];
}

extern "C" void kernel_launch(void* const* d_in, const int* in_sizes, int n_in,
                              void* d_out, int out_size, void* d_ws, size_t ws_size,
                              hipStream_t stream) {
  const float* core = (const float*)d_in[0];
  const float* ligs = (const float*)d_in[1];
  const float* W1   = (const float*)d_in[2];
  const float* b1   = (const float*)d_in[3];
  const float* W2   = (const float*)d_in[4];
  const float* b2   = (const float*)d_in[5];
  const float* W3   = (const float*)d_in[6];
  const float* b3   = (const float*)d_in[7];
  float* out = (float*)d_out;
  char*  ws  = (char*)d_ws;                 // 29 KB used; fill is sunk cost

  const int B = in_sizes[0] / 64;           // 32768
  const int grid = B / BPB;                 // 1024

  prep<<<dim3(57), dim3(256), 0, stream>>>(W1, b1, W2, b2, W3, ws);

  (void)hipFuncSetAttribute((const void*)tb_fused,
                            hipFuncAttributeMaxDynamicSharedMemorySize, LDS_BYTES);
  tb_fused<<<dim3(grid), dim3(NT), LDS_BYTES, stream>>>(
      core, ligs, ws, b3, out);
}